// Round 18
// baseline (492.726 us; speedup 1.0000x reference)
//
#include <hip/hip_runtime.h>
#include <hip/hip_bf16.h>
#include <hip/hip_fp16.h>
#include <math.h>

#define NB 128     // batch
#define NC 512     // channels
#define NT 40      // time steps
#define HW 512     // nH*nW
#define HL 256     // LSTM hidden per direction
#define NG 5000    // nclass
#define XDIM 1024  // 2*NC (GRU input)
#define G4 1024    // 4*HL
#define G3 1536    // 3*NC

typedef _Float16 f16x8 __attribute__((ext_vector_type(8)));
typedef short s16x8 __attribute__((ext_vector_type(8)));
typedef float f32x4_ __attribute__((ext_vector_type(4)));

__device__ __forceinline__ float sigm(float x) { return 1.f / (1.f + expf(-x)); }
__device__ __forceinline__ ushort f2hs(float f) {
  _Float16 h = (_Float16)f;
  return __builtin_bit_cast(ushort, h);
}
__device__ __forceinline__ uint32_t f2bf(float f) {
  uint32_t u = __float_as_uint(f);
  return (u + 0x7fffu + ((u >> 16) & 1u)) >> 16;
}
__device__ __forceinline__ float bf2f(ushort u) {
  return __uint_as_float((uint32_t)u << 16);
}

// L2-bypass (sc1) 16B load as f16x8, via two agent-scope relaxed u64 loads
__device__ __forceinline__ f16x8 coh_load16(const ushort* p) {
  unsigned long long lo = __hip_atomic_load((const unsigned long long*)p,
                                            __ATOMIC_RELAXED, __HIP_MEMORY_SCOPE_AGENT);
  unsigned long long hi = __hip_atomic_load((const unsigned long long*)(p + 4),
                                            __ATOMIC_RELAXED, __HIP_MEMORY_SCOPE_AGENT);
  union { unsigned long long q[2]; f16x8 v; } u;
  u.q[0] = lo; u.q[1] = hi;
  return u.v;
}

// ---------------------------------------------------------------------------
// small setup kernels
// ---------------------------------------------------------------------------
__global__ void offsets_kernel(const int* __restrict__ tl, int* __restrict__ offs) {
  if (threadIdx.x == 0) {
    int o = 0;
    for (int b = 0; b < NB; ++b) { offs[b] = o; o += tl[b]; }
  }
}

__global__ void rowmap_kernel(const int* __restrict__ tl, const int* __restrict__ offs,
                              int* __restrict__ rowmap) {
  int b = blockIdx.x;
  int len = tl[b], off = offs[b];
  for (int t = threadIdx.x; t < len; t += blockDim.x)
    rowmap[off + t] = t * NB + b;   // row index into [t][b][*] matrices
}

__global__ void zero_kernel(int* __restrict__ p, int n) {
  int i = blockIdx.x * 256 + threadIdx.x;
  if (i < n) p[i] = 0;
}

// concat LSTM input-proj biases: [0:1024)=bih_f, [1024:2048)=bih_b
__global__ void biascat_kernel(const float* __restrict__ bf, const float* __restrict__ bb,
                               float* __restrict__ o) {
  int i = blockIdx.x * 256 + threadIdx.x;
  if (i < G4) o[i] = bf[i];
  else if (i < 2 * G4) o[i] = bb[i - G4];
}

// 1/sum over HW per (b,t)
__global__ __launch_bounds__(64) void asum_kernel(const float* __restrict__ A,
                                                  float* __restrict__ out) {
  int row = blockIdx.x;  // b*NT + t
  const float* p = A + (size_t)row * HW;
  float s = 0.f;
#pragma unroll
  for (int i = 0; i < 8; ++i) s += p[threadIdx.x + i * 64];
#pragma unroll
  for (int off = 32; off > 0; off >>= 1) s += __shfl_down(s, off);
  if (threadIdx.x == 0) out[row] = 1.0f / s;
}

// teacher-forcing embedding into x16[:,:,512:1024] (bf16)
__global__ __launch_bounds__(128) void emb_kernel(const float* __restrict__ ce,
                                                  const int* __restrict__ text,
                                                  const int* __restrict__ tl,
                                                  const int* __restrict__ offs,
                                                  ushort* __restrict__ x16) {
  int bid = blockIdx.x;  // t*NB + b
  int t = bid >> 7, b = bid & 127;
  int tok = 0;
  if (t >= 2) {
    int p = t - 2;
    if (p < tl[b]) tok = text[offs[b] + p] + 1;
  }
  float4 v = *(const float4*)(ce + (size_t)tok * NC + threadIdx.x * 4);
  ushort4 u;
  u.x = (ushort)f2bf(v.x); u.y = (ushort)f2bf(v.y);
  u.z = (ushort)f2bf(v.z); u.w = (ushort)f2bf(v.w);
  *(ushort4*)(x16 + (size_t)bid * XDIM + NC + threadIdx.x * 4) = u;
}

// f32 -> bf16 bulk convert (n4 = count/4)
__global__ __launch_bounds__(256) void cvtbf_kernel(const float* __restrict__ in,
                                                    ushort* __restrict__ out, int n4) {
  int i = blockIdx.x * 256 + threadIdx.x;
  if (i >= n4) return;
  float4 v = ((const float4*)in)[i];
  ushort4 o;
  o.x = (ushort)f2bf(v.x); o.y = (ushort)f2bf(v.y);
  o.z = (ushort)f2bf(v.z); o.w = (ushort)f2bf(v.w);
  ((ushort4*)out)[i] = o;
}

// f32 -> f16 bulk convert (n4 = count/4)
__global__ __launch_bounds__(256) void cvtf16_kernel(const float* __restrict__ in,
                                                     ushort* __restrict__ out, int n4) {
  int i = blockIdx.x * 256 + threadIdx.x;
  if (i >= n4) return;
  float4 v = ((const float4*)in)[i];
  ushort4 o;
  o.x = f2hs(v.x); o.y = f2hs(v.y); o.z = f2hs(v.z); o.w = f2hs(v.w);
  ((ushort4*)out)[i] = o;
}

// ---------------------------------------------------------------------------
// attention-pool MFMA kernel (R17-proven): per-b GEMM, fused f32->bf16
// staging, asum folded into B. Writes Cbf[(t*NB+b)*NC + c] bf16.
// ---------------------------------------------------------------------------
__global__ __launch_bounds__(256) void pool_mfma_kernel(
    const float* __restrict__ feat,   // [NB][NC][HW]
    const float* __restrict__ A,      // [NB][NT][HW]
    const float* __restrict__ asum,   // [NB*NT] = 1/sum
    ushort* __restrict__ Cbf) {       // [NT*NB][NC]
  __shared__ __align__(16) ushort Al[128 * 40];
  __shared__ __align__(16) ushort Bl[128 * 40];
  const int b = blockIdx.z;
  const int m0 = blockIdx.y * 128;
  const int tid = threadIdx.x;
  const int lane = tid & 63, wid = tid >> 6;
  const int wm = (wid >> 1) * 64, wn = (wid & 1) * 64;
  const int lr = lane & 15, lk = lane >> 4;

  f32x4_ acc[4][4];
#pragma unroll
  for (int i = 0; i < 4; ++i)
#pragma unroll
    for (int j = 0; j < 4; ++j) {
      acc[i][j][0] = 0.f; acc[i][j][1] = 0.f;
      acc[i][j][2] = 0.f; acc[i][j][3] = 0.f;
    }

  for (int k0 = 0; k0 < HW; k0 += 32) {
    __syncthreads();
#pragma unroll
    for (int it = 0; it < 2; ++it) {
      int ch = tid + it * 256;          // 0..511
      int rr = ch >> 2, kq = (ch & 3) * 8;
      const float* fa = feat + ((size_t)b * NC + (m0 + rr)) * HW + k0 + kq;
      float4 a0 = *(const float4*)fa;
      float4 a1 = *(const float4*)(fa + 4);
      ushort av[8] = {(ushort)f2bf(a0.x), (ushort)f2bf(a0.y), (ushort)f2bf(a0.z),
                      (ushort)f2bf(a0.w), (ushort)f2bf(a1.x), (ushort)f2bf(a1.y),
                      (ushort)f2bf(a1.z), (ushort)f2bf(a1.w)};
      *(uint4*)&Al[rr * 40 + kq] = *(const uint4*)av;
      int t = rr < NT ? rr : NT - 1;
      float s = asum[b * NT + t];
      const float* fb = A + ((size_t)b * NT + t) * HW + k0 + kq;
      float4 b0 = *(const float4*)fb;
      float4 b1 = *(const float4*)(fb + 4);
      ushort bv[8] = {(ushort)f2bf(b0.x * s), (ushort)f2bf(b0.y * s),
                      (ushort)f2bf(b0.z * s), (ushort)f2bf(b0.w * s),
                      (ushort)f2bf(b1.x * s), (ushort)f2bf(b1.y * s),
                      (ushort)f2bf(b1.z * s), (ushort)f2bf(b1.w * s)};
      *(uint4*)&Bl[rr * 40 + kq] = *(const uint4*)bv;
    }
    __syncthreads();
    s16x8 af[4], bf[4];
#pragma unroll
    for (int i = 0; i < 4; ++i)
      af[i] = *(const s16x8*)&Al[(wm + i * 16 + lr) * 40 + lk * 8];
#pragma unroll
    for (int i = 0; i < 4; ++i)
      bf[i] = *(const s16x8*)&Bl[(wn + i * 16 + lr) * 40 + lk * 8];
#pragma unroll
    for (int i = 0; i < 4; ++i)
#pragma unroll
      for (int j = 0; j < 4; ++j)
        acc[i][j] = __builtin_amdgcn_mfma_f32_16x16x32_bf16(af[i], bf[j], acc[i][j], 0, 0, 0);
  }

#pragma unroll
  for (int i = 0; i < 4; ++i) {
#pragma unroll
    for (int j = 0; j < 4; ++j) {
      int t = wn + j * 16 + lr;
      if (t >= NT) continue;
#pragma unroll
      for (int r = 0; r < 4; ++r) {
        int c = m0 + wm + i * 16 + lk * 4 + r;
        Cbf[((size_t)t * NB + b) * NC + c] = (ushort)f2bf(acc[i][j][r]);
      }
    }
  }
}

// ---------------------------------------------------------------------------
// bf16 MFMA GEMM (R14-proven): 128x128 tile, 4 waves 2x2, 16x16x32 mfma.
// global_load_lds staging with XOR-swizzled layout.
// ---------------------------------------------------------------------------
#if __has_builtin(__builtin_amdgcn_global_load_lds)
#define MG_ASYNC 1
#endif

#ifdef MG_ASYNC
#define MG_LDT 32
#else
#define MG_LDT 40
#endif

__global__ __launch_bounds__(256) void mgemm_kernel(
    int M, int N, int K,
    const ushort* __restrict__ A, const int* __restrict__ rowmap,
    const ushort* __restrict__ B, const float* __restrict__ bias,
    void* __restrict__ outp, long ldo, int outBf) {
  __shared__ __align__(16) ushort Al[128 * MG_LDT];
  __shared__ __align__(16) ushort Bl[128 * MG_LDT];
  const int m0 = blockIdx.y * 128, n0 = blockIdx.x * 128;
  const int tid = threadIdx.x;
  const int lane = tid & 63, wid = tid >> 6;
  const int wm = (wid >> 1) * 64, wn = (wid & 1) * 64;
  const int lr = lane & 15, lk = lane >> 4;

  f32x4_ acc[4][4];
#pragma unroll
  for (int i = 0; i < 4; ++i)
#pragma unroll
    for (int j = 0; j < 4; ++j) {
      acc[i][j][0] = 0.f; acc[i][j][1] = 0.f;
      acc[i][j][2] = 0.f; acc[i][j][3] = 0.f;
    }

#ifdef MG_ASYNC
  const int swsrc = (((lane & 3) ^ ((lane >> 2) & 3) ^ ((lane >> 4) & 3))) * 8;
  const int sA = (lr & 3) ^ ((lr >> 2) & 3);      // s(R) for read rows
  const int kofs = (lk ^ sA) * 8;                 // swizzled ushort col offset
#endif

  for (int k0 = 0; k0 < K; k0 += 32) {
    __syncthreads();
#ifdef MG_ASYNC
#pragma unroll
    for (int it = 0; it < 2; ++it) {
      const int qq = wid * 2 + it;                 // 16-row chunk, wave-uniform
      const int row = qq * 16 + (lane >> 2);       // local tile row
      int gm = m0 + row; if (gm >= M) gm = M - 1;
      long ar = rowmap ? (long)rowmap[gm] : (long)gm;
      const ushort* ga = A + ar * (long)K + k0 + swsrc;
      __builtin_amdgcn_global_load_lds(
          (const __attribute__((address_space(1))) void*)ga,
          (__attribute__((address_space(3))) void*)&Al[qq * 512], 16, 0, 0);
      int gn = n0 + row; if (gn >= N) gn = N - 1;
      const ushort* gb = B + (long)gn * K + k0 + swsrc;
      __builtin_amdgcn_global_load_lds(
          (const __attribute__((address_space(1))) void*)gb,
          (__attribute__((address_space(3))) void*)&Bl[qq * 512], 16, 0, 0);
    }
#else
#pragma unroll
    for (int it = 0; it < 2; ++it) {
      int ch = tid + it * 256;          // 0..511
      int rr = ch >> 2, kq = (ch & 3) * 8;
      int gm = m0 + rr; if (gm >= M) gm = M - 1;
      long ar = rowmap ? (long)rowmap[gm] : (long)gm;
      uint4 av = *(const uint4*)(A + ar * (long)K + k0 + kq);
      int gn = n0 + rr; if (gn >= N) gn = N - 1;
      uint4 bv = *(const uint4*)(B + (long)gn * K + k0 + kq);
      *(uint4*)&Al[rr * MG_LDT + kq] = av;
      *(uint4*)&Bl[rr * MG_LDT + kq] = bv;
    }
#endif
    __syncthreads();
    s16x8 af[4], bf[4];
#ifdef MG_ASYNC
#pragma unroll
    for (int i = 0; i < 4; ++i)
      af[i] = *(const s16x8*)&Al[(wm + i * 16 + lr) * 32 + kofs];
#pragma unroll
    for (int i = 0; i < 4; ++i)
      bf[i] = *(const s16x8*)&Bl[(wn + i * 16 + lr) * 32 + kofs];
#else
#pragma unroll
    for (int i = 0; i < 4; ++i)
      af[i] = *(const s16x8*)&Al[(wm + i * 16 + lr) * MG_LDT + lk * 8];
#pragma unroll
    for (int i = 0; i < 4; ++i)
      bf[i] = *(const s16x8*)&Bl[(wn + i * 16 + lr) * MG_LDT + lk * 8];
#endif
#pragma unroll
    for (int i = 0; i < 4; ++i)
#pragma unroll
      for (int j = 0; j < 4; ++j)
        acc[i][j] = __builtin_amdgcn_mfma_f32_16x16x32_bf16(af[i], bf[j], acc[i][j], 0, 0, 0);
  }

#pragma unroll
  for (int i = 0; i < 4; ++i) {
#pragma unroll
    for (int j = 0; j < 4; ++j) {
      int n = n0 + wn + j * 16 + lr;
      if (n >= N) continue;
      float bv = bias ? bias[n] : 0.f;
#pragma unroll
      for (int r = 0; r < 4; ++r) {
        int m = m0 + wm + i * 16 + lk * 4 + r;
        if (m >= M) continue;
        float v = acc[i][j][r] + bv;
        if (outBf) ((ushort*)outp)[(long)m * ldo + n] = (ushort)f2bf(v);
        else       ((float*)outp)[(long)m * ldo + n] = v;
      }
    }
  }
}

// ---------------------------------------------------------------------------
// LSTM sync recurrence (R17-proven; xg combined bf16 stride-2048):
// 64 blocks = 2 dirs x 4 batch-groups(32) x 8 j-chunks(32), 256 thr.
// ---------------------------------------------------------------------------
__global__ __launch_bounds__(256) void lstm_sync_kernel(
    const ushort* __restrict__ xgc,   // bf16 [NT*NB][2*G4]: cols dir*1024+g*256+j
    const ushort* __restrict__ W16,   // f16 [2][4*HL][HL]
    const float* __restrict__ bhh_f, const float* __restrict__ bhh_b,
    ushort* __restrict__ hbufL,       // f16 [2][2][8][NB][32]
    ushort* __restrict__ x16,         // bf16 [NT*NB][XDIM]
    int* __restrict__ flags) {
  const int dir = blockIdx.x >> 5;
  const int bg = (blockIdx.x >> 3) & 3;
  const int jc = blockIdx.x & 7;
  const float* bhh = dir ? bhh_b : bhh_f;
  const ushort* W = W16 + (size_t)dir * 4 * HL * HL;
  const int tid = threadIdx.x;
  const int lane = tid & 63, wid = tid >> 6;
  const int mt = wid >> 1, jsub = wid & 1;
  const int lr = lane & 15, lk = lane >> 4;

  __shared__ __align__(16) ushort Wl[8 * 128 * 40];  // [ktile][g*32+jj][40]

  // stage W chunk into LDS (one-time): 4096 uint4
  for (int i = tid; i < 4096; i += 256) {
    int kt = i >> 9, rem = i & 511;
    int row = rem >> 2, kq = rem & 3;
    int g = row >> 5, jj = row & 31;
    const ushort* src = W + ((size_t)(g * HL + jc * 32 + jj)) * HL + kt * 32 + kq * 8;
    *(uint4*)&Wl[(kt * 128 + row) * 40 + kq * 8] = *(const uint4*)src;
  }
  // zero own h slice (ping 0) with sc1 stores
  for (int i = tid; i < 1024; i += 256) {
    int bb = i >> 5, jl2 = i & 31;
    __hip_atomic_store(
        &hbufL[(((size_t)dir) * 8 + jc) * NB * 32 + (size_t)(bg * 32 + bb) * 32 + jl2],
        (ushort)0, __ATOMIC_RELAXED, __HIP_MEMORY_SCOPE_AGENT);
  }

  int* gfl = flags + (dir * 4 + bg) * 64;
  const int jl = jsub * 16 + lr;
  const int jg = jc * 32 + jl;
  const int bbase = bg * 32 + mt * 16;
  const int xcol = dir * G4 + jg;     // base col in combined xg
  const float bbi = bhh[jg], bbf = bhh[HL + jg];
  const float bbg = bhh[2 * HL + jg], bbo = bhh[3 * HL + jg];
  float creg[4] = {0.f, 0.f, 0.f, 0.f};
  float pxi[4], pxf[4], pxg[4], pxo[4];

  auto pref = [&](int s) {
    int tt = dir ? (NT - 1 - s) : s;
#pragma unroll
    for (int r = 0; r < 4; ++r) {
      int b = bbase + lk * 4 + r;
      const ushort* p = xgc + ((long)tt * NB + b) * (2 * G4) + xcol;
      pxi[r] = bf2f(p[0]);
      pxf[r] = bf2f(p[HL]);
      pxg[r] = bf2f(p[2 * HL]);
      pxo[r] = bf2f(p[3 * HL]);
    }
  };

  auto bar = [&](int step, int prefs) {
    __syncthreads();
    if (tid == 0)
      __hip_atomic_store(&gfl[jc], step, __ATOMIC_RELAXED, __HIP_MEMORY_SCOPE_AGENT);
    if (prefs >= 0) pref(prefs);
    if (tid < 8) {
      while (__hip_atomic_load(&gfl[tid], __ATOMIC_RELAXED, __HIP_MEMORY_SCOPE_AGENT) < step)
        __builtin_amdgcn_s_sleep(1);
    }
    __syncthreads();
  };

  bar(1, 0);   // publish W-stage-done + h zeros; prefetch xg(0)

  for (int s = 0; s < NT; ++s) {
    const int p = s & 1;
    const int tt = dir ? (NT - 1 - s) : s;
    f16x8 ha[8];
#pragma unroll
    for (int kt = 0; kt < 8; ++kt)
      ha[kt] = coh_load16(hbufL + (((size_t)p * 2 + dir) * 8 + kt) * NB * 32 +
                          (size_t)(bbase + lr) * 32 + lk * 8);
    f32x4_ ai = {0.f, 0.f, 0.f, 0.f};
    f32x4_ af = {0.f, 0.f, 0.f, 0.f};
    f32x4_ ag = {0.f, 0.f, 0.f, 0.f};
    f32x4_ ao = {0.f, 0.f, 0.f, 0.f};
#pragma unroll
    for (int kt = 0; kt < 8; ++kt) {
      f16x8 bi = *(const f16x8*)&Wl[(kt * 128 + 0  + jl) * 40 + lk * 8];
      f16x8 bf = *(const f16x8*)&Wl[(kt * 128 + 32 + jl) * 40 + lk * 8];
      f16x8 bg_ = *(const f16x8*)&Wl[(kt * 128 + 64 + jl) * 40 + lk * 8];
      f16x8 bo = *(const f16x8*)&Wl[(kt * 128 + 96 + jl) * 40 + lk * 8];
      ai = __builtin_amdgcn_mfma_f32_16x16x32_f16(ha[kt], bi, ai, 0, 0, 0);
      af = __builtin_amdgcn_mfma_f32_16x16x32_f16(ha[kt], bf, af, 0, 0, 0);
      ag = __builtin_amdgcn_mfma_f32_16x16x32_f16(ha[kt], bg_, ag, 0, 0, 0);
      ao = __builtin_amdgcn_mfma_f32_16x16x32_f16(ha[kt], bo, ao, 0, 0, 0);
    }
    ushort* hwc = hbufL + (((size_t)(p ^ 1) * 2 + dir) * 8 + jc) * NB * 32;
#pragma unroll
    for (int r = 0; r < 4; ++r) {
      int b = bbase + lk * 4 + r;
      long row = (long)tt * NB + b;
      float gi = pxi[r] + ai[r] + bbi;
      float gf = pxf[r] + af[r] + bbf;
      float gg = pxg[r] + ag[r] + bbg;
      float go = pxo[r] + ao[r] + bbo;
      creg[r] = sigm(gf) * creg[r] + sigm(gi) * tanhf(gg);
      float hn = sigm(go) * tanhf(creg[r]);
      __hip_atomic_store(&hwc[(size_t)b * 32 + jl], f2hs(hn),
                         __ATOMIC_RELAXED, __HIP_MEMORY_SCOPE_AGENT);
      x16[row * XDIM + dir * HL + jg] = (ushort)f2bf(hn);
    }
    if (s + 1 < NT) bar(s + 2, s + 1);
  }
}

// ---------------------------------------------------------------------------
// GRU sync recurrence (R15-proven): 64 blocks = 4 batch-groups x 16 j-chunks.
// ---------------------------------------------------------------------------
__global__ __launch_bounds__(256) void gru_sync_kernel(
    const ushort* __restrict__ xg,    // bf16 [NT*NB][G3]
    const ushort* __restrict__ Wf,    // f16 [G3][NC]
    const float* __restrict__ bhh,
    ushort* __restrict__ hbuf,        // f16 chunked [2][16][NB][32]
    ushort* __restrict__ gout,        // bf16 flat [NT*NB][NC]
    int* __restrict__ flags) {
  const int bg = blockIdx.x >> 4, jc = blockIdx.x & 15;
  const int tid = threadIdx.x;
  const int lane = tid & 63, wid = tid >> 6;
  const int mt = wid >> 1, jsub = wid & 1;
  const int lr = lane & 15, lk = lane >> 4;

  __shared__ __align__(16) ushort Wl[16 * 96 * 40];  // [ktile][g*32+jj][40]

  for (int i = tid; i < 6144; i += 256) {
    int kt = i / 384, rem = i - kt * 384;
    int row = rem >> 2, kq = rem & 3;
    int g = row >> 5, jj = row & 31;
    const ushort* src = Wf + ((size_t)(g * NC + jc * 32 + jj)) * NC + kt * 32 + kq * 8;
    *(uint4*)&Wl[(kt * 96 + row) * 40 + kq * 8] = *(const uint4*)src;
  }
  for (int i = tid; i < 1024; i += 256) {
    int bb = i >> 5, jl2 = i & 31;
    __hip_atomic_store(&hbuf[((size_t)jc * NB + (bg * 32 + bb)) * 32 + jl2],
                       (ushort)0, __ATOMIC_RELAXED, __HIP_MEMORY_SCOPE_AGENT);
  }

  int* gfl = flags + bg * 64;                // 256B per group
  const int jl = jsub * 16 + lr;             // local j within chunk
  const int jg = jc * 32 + jl;               // global j
  const int bbase = bg * 32 + mt * 16;       // A/C m-tile batch base
  const float bb0 = bhh[jg], bb1 = bhh[NC + jg], bb2 = bhh[2 * NC + jg];
  float hreg[4] = {0.f, 0.f, 0.f, 0.f};
  float pxr[4], pxz[4], pxn[4];

  auto pref = [&](int t) {
#pragma unroll
    for (int r = 0; r < 4; ++r) {
      int b = bbase + lk * 4 + r;
      long row = (long)t * NB + b;
      pxr[r] = bf2f(xg[row * G3 + jg]);
      pxz[r] = bf2f(xg[row * G3 + NC + jg]);
      pxn[r] = bf2f(xg[row * G3 + 2 * NC + jg]);
    }
  };

  auto bar = [&](int step, int preft) {
    __syncthreads();
    if (tid == 0)
      __hip_atomic_store(&gfl[jc], step, __ATOMIC_RELAXED, __HIP_MEMORY_SCOPE_AGENT);
    if (preft >= 0) pref(preft);
    if (tid < 16) {
      while (__hip_atomic_load(&gfl[tid], __ATOMIC_RELAXED, __HIP_MEMORY_SCOPE_AGENT) < step)
        __builtin_amdgcn_s_sleep(1);
    }
    __syncthreads();
  };

  bar(1, 0);   // publish W-stage-done + h zeros; prefetch xg(0)

  for (int t = 0; t < NT; ++t) {
    const int p = t & 1;
    f16x8 ha[16];
#pragma unroll
    for (int kt = 0; kt < 16; ++kt)
      ha[kt] = coh_load16(hbuf + ((size_t)(p * 16 + kt) * NB + (bbase + lr)) * 32 + lk * 8);
    f32x4_ ar = {0.f, 0.f, 0.f, 0.f};
    f32x4_ az = {0.f, 0.f, 0.f, 0.f};
    f32x4_ an = {0.f, 0.f, 0.f, 0.f};
#pragma unroll
    for (int kt = 0; kt < 16; ++kt) {
      f16x8 br = *(const f16x8*)&Wl[(kt * 96 + 0  + jl) * 40 + lk * 8];
      f16x8 bz = *(const f16x8*)&Wl[(kt * 96 + 32 + jl) * 40 + lk * 8];
      f16x8 bn = *(const f16x8*)&Wl[(kt * 96 + 64 + jl) * 40 + lk * 8];
      ar = __builtin_amdgcn_mfma_f32_16x16x32_f16(ha[kt], br, ar, 0, 0, 0);
      az = __builtin_amdgcn_mfma_f32_16x16x32_f16(ha[kt], bz, az, 0, 0, 0);
      an = __builtin_amdgcn_mfma_f32_16x16x32_f16(ha[kt], bn, an, 0, 0, 0);
    }
    ushort* hwc = hbuf + ((size_t)((p ^ 1) * 16 + jc)) * NB * 32;
#pragma unroll
    for (int r = 0; r < 4; ++r) {
      int b = bbase + lk * 4 + r;
      long row = (long)t * NB + b;
      float rr = sigm(pxr[r] + ar[r] + bb0);
      float zz = sigm(pxz[r] + az[r] + bb1);
      float nn = tanhf(pxn[r] + rr * (an[r] + bb2));
      float h = (1.f - zz) * nn + zz * hreg[r];
      hreg[r] = h;
      __hip_atomic_store(&hwc[(size_t)b * 32 + jl], f2hs(h),
                         __ATOMIC_RELAXED, __HIP_MEMORY_SCOPE_AGENT);
      gout[row * NC + jg] = (ushort)f2bf(h);
    }
    if (t + 1 < NT) bar(t + 2, t + 1);
  }
}

// ---------------------------------------------------------------------------
extern "C" void kernel_launch(void* const* d_in, const int* in_sizes, int n_in,
                              void* d_out, int out_size, void* d_ws, size_t ws_size,
                              hipStream_t stream) {
  const float* feature = (const float*)d_in[0];
  const float* A       = (const float*)d_in[1];
  const int*   text    = (const int*)d_in[2];
  const int*   tlen    = (const int*)d_in[3];
  const float* Wih_f   = (const float*)d_in[4];
  const float* Whh_f   = (const float*)d_in[5];
  const float* bih_f   = (const float*)d_in[6];
  const float* bhh_f   = (const float*)d_in[7];
  const float* Wih_b   = (const float*)d_in[8];
  const float* Whh_b   = (const float*)d_in[9];
  const float* bih_b   = (const float*)d_in[10];
  const float* bhh_b   = (const float*)d_in[11];
  const float* gWih    = (const float*)d_in[12];
  const float* gWhh    = (const float*)d_in[13];
  const float* gbih    = (const float*)d_in[14];
  const float* gbhh    = (const float*)d_in[15];
  const float* genW    = (const float*)d_in[16];
  const float* genb    = (const float*)d_in[17];
  const float* cemb    = (const float*)d_in[18];
  float* out = (float*)d_out;
  const int total = in_sizes[2];

  char* ws = (char*)d_ws;
  size_t off = 0;
  auto alloc = [&](size_t bytes) -> void* {
    void* p = ws + off;
    off += (bytes + 255) & ~(size_t)255;
    return p;
  };
  float*    asum   = (float*)alloc((size_t)NB * NT * 4);
  int*      offs   = (int*)alloc(NB * 4);
  int*      rowmap = (int*)alloc((size_t)NB * NT * 4);
  int*      flags  = (int*)alloc(12 * 64 * 4);                  // GRU 4 + LSTM 8 groups
  float*    biascat= (float*)alloc(2 * G4 * 4);
  ushort*   xgcat  = (ushort*)alloc((size_t)NT * NB * 2 * G4 * 2); // 21MB bf16; later gxg
  ushort*   xbuf_bf= (ushort*)alloc((size_t)NT * NB * XDIM * 2);// 10.5MB: x bf16
  ushort*   WgL    = (ushort*)alloc((size_t)2 * 4 * HL * HL * 2);  // LSTM Whh f16, 1 MB
  ushort*   Wg16   = (ushort*)alloc((size_t)G3 * NC * 2);       // GRU Whh f16, 1.5 MB
  ushort*   Wcat   = (ushort*)alloc((size_t)2 * G4 * NC * 2);   // LSTM Wih concat bf16, 2 MB
  ushort*   gWih_bf= (ushort*)alloc((size_t)G3 * XDIM * 2);     // 3 MB
  ushort*   genW_bf= (ushort*)alloc((size_t)NG * NC * 2);       // 5.12 MB
  ushort*   hbuf   = (ushort*)alloc((size_t)2 * 16 * NB * 32 * 2);    // GRU h, 256KB
  ushort*   hbufL  = (ushort*)alloc((size_t)2 * 2 * 8 * NB * 32 * 2); // LSTM h, 256KB
  ushort*   Cbf    = (ushort*)alloc((size_t)NT * NB * NC * 2);  // 5.25MB: C bf16 / gout bf16
  ushort*   gxg    = xgcat;                                     // bf16 [5120][1536] (after lstm)
  ushort*   gout_bf = Cbf;

  // --- setup + ALL weight converts up front (off critical path) ---
  offsets_kernel<<<1, 64, 0, stream>>>(tlen, offs);
  rowmap_kernel<<<NB, 64, 0, stream>>>(tlen, offs, rowmap);
  zero_kernel<<<3, 256, 0, stream>>>(flags, 768);
  biascat_kernel<<<8, 256, 0, stream>>>(bih_f, bih_b, biascat);
  asum_kernel<<<NB * NT, 64, 0, stream>>>(A, asum);
  cvtf16_kernel<<<256, 256, 0, stream>>>(Whh_f, WgL, 4 * HL * HL / 4);
  cvtf16_kernel<<<256, 256, 0, stream>>>(Whh_b, WgL + 4 * HL * HL, 4 * HL * HL / 4);
  cvtf16_kernel<<<768, 256, 0, stream>>>(gWhh, Wg16, G3 * NC / 4);
  cvtbf_kernel<<<512, 256, 0, stream>>>(Wih_f, Wcat, G4 * NC / 4);
  cvtbf_kernel<<<512, 256, 0, stream>>>(Wih_b, Wcat + (size_t)G4 * NC, G4 * NC / 4);
  cvtbf_kernel<<<1536, 256, 0, stream>>>(gWih, gWih_bf, G3 * XDIM / 4);
  cvtbf_kernel<<<2500, 256, 0, stream>>>(genW, genW_bf, NG * NC / 4);

  // --- attention pooling: fused f32->bf16 MFMA, writes Cbf directly ---
  pool_mfma_kernel<<<dim3(1, 4, NB), 256, 0, stream>>>(feature, A, asum, Cbf);

  // --- LSTM input projections: ONE fused mgemm (N=2048) -> xgcat bf16 ---
  mgemm_kernel<<<dim3(2 * G4 / 128, NT * NB / 128), 256, 0, stream>>>(
      NT * NB, 2 * G4, NC, Cbf, nullptr, Wcat, biascat, xgcat, (long)(2 * G4), 1);

  // --- LSTM recurrence: sync groups, LDS-resident W, writes bf16 x ---
  lstm_sync_kernel<<<64, 256, 0, stream>>>(
      xgcat, WgL, bhh_f, bhh_b, hbufL, xbuf_bf, flags + 256);

  // --- embedding into x[:,:,512:1024] (bf16) ---
  emb_kernel<<<NT * NB, 128, 0, stream>>>(cemb, text, tlen, offs, xbuf_bf);

  // --- GRU input projection (xgcat consumed -> gxg reuses its region) ---
  mgemm_kernel<<<dim3(G3 / 128, NT * NB / 128), 256, 0, stream>>>(
      NT * NB, G3, XDIM, xbuf_bf, nullptr, gWih_bf, gbih, gxg, (long)G3, 1);

  // --- GRU recurrence: sync groups, sc1 h exchange, flat gout ---
  gru_sync_kernel<<<64, 256, 0, stream>>>(gxg, Wg16, gbhh, hbuf, gout_bf, flags);

  // --- vocab projection, ragged rows straight into d_out ---
  mgemm_kernel<<<dim3((NG + 127) / 128, (total + 127) / 128), 256, 0, stream>>>(
      total, NG, NC, gout_bf, rowmap, genW_bf, genb, out, (long)NG, 0);
}

// Round 19
// 469.448 us; speedup vs baseline: 1.0496x; 1.0496x over previous
//
#include <hip/hip_runtime.h>
#include <hip/hip_bf16.h>
#include <hip/hip_fp16.h>
#include <math.h>

#define NB 128     // batch
#define NC 512     // channels
#define NT 40      // time steps
#define HW 512     // nH*nW
#define HL 256     // LSTM hidden per direction
#define NG 5000    // nclass
#define XDIM 1024  // 2*NC (GRU input)
#define G4 1024    // 4*HL
#define G3 1536    // 3*NC

typedef _Float16 f16x8 __attribute__((ext_vector_type(8)));
typedef short s16x8 __attribute__((ext_vector_type(8)));
typedef float f32x4_ __attribute__((ext_vector_type(4)));

__device__ __forceinline__ float sigm(float x) { return 1.f / (1.f + expf(-x)); }
__device__ __forceinline__ ushort f2hs(float f) {
  _Float16 h = (_Float16)f;
  return __builtin_bit_cast(ushort, h);
}
__device__ __forceinline__ uint32_t f2bf(float f) {
  uint32_t u = __float_as_uint(f);
  return (u + 0x7fffu + ((u >> 16) & 1u)) >> 16;
}
__device__ __forceinline__ float bf2f(ushort u) {
  return __uint_as_float((uint32_t)u << 16);
}

// L2-bypass (sc1) 16B load as f16x8, via two agent-scope relaxed u64 loads
__device__ __forceinline__ f16x8 coh_load16(const ushort* p) {
  unsigned long long lo = __hip_atomic_load((const unsigned long long*)p,
                                            __ATOMIC_RELAXED, __HIP_MEMORY_SCOPE_AGENT);
  unsigned long long hi = __hip_atomic_load((const unsigned long long*)(p + 4),
                                            __ATOMIC_RELAXED, __HIP_MEMORY_SCOPE_AGENT);
  union { unsigned long long q[2]; f16x8 v; } u;
  u.q[0] = lo; u.q[1] = hi;
  return u.v;
}

// ---------------------------------------------------------------------------
// fused prep kernel: all setup work in ONE launch, segmented by blockIdx.
//  [0,1)        offsets (serial)
//  [1,4)        zero flags (768 ints)
//  [4,12)       biascat (2048 floats)
//  [12,140)     rowmap (block computes own prefix)
//  [140,1420)   asum: 4 rows/block, wave-local reduce
//  [1420,1676)  cvtf16 Whh_f -> WgL
//  [1676,1932)  cvtf16 Whh_b -> WgL+
//  [1932,2700)  cvtf16 gWhh  -> Wg16
//  [2700,3212)  cvtbf  Wih_f -> Wcat
//  [3212,3724)  cvtbf  Wih_b -> Wcat+
//  [3724,5260)  cvtbf  gWih  -> gWih_bf
//  [5260,7760)  cvtbf  genW  -> genW_bf
// ---------------------------------------------------------------------------
__device__ __forceinline__ void seg_cvtf16(const float* in, ushort* out, int n4, int blk) {
  int i = blk * 256 + (int)threadIdx.x;
  if (i >= n4) return;
  float4 v = ((const float4*)in)[i];
  ushort4 o;
  o.x = f2hs(v.x); o.y = f2hs(v.y); o.z = f2hs(v.z); o.w = f2hs(v.w);
  ((ushort4*)out)[i] = o;
}
__device__ __forceinline__ void seg_cvtbf(const float* in, ushort* out, int n4, int blk) {
  int i = blk * 256 + (int)threadIdx.x;
  if (i >= n4) return;
  float4 v = ((const float4*)in)[i];
  ushort4 o;
  o.x = (ushort)f2bf(v.x); o.y = (ushort)f2bf(v.y);
  o.z = (ushort)f2bf(v.z); o.w = (ushort)f2bf(v.w);
  ((ushort4*)out)[i] = o;
}

__global__ __launch_bounds__(256) void prep_kernel(
    const int* __restrict__ tlen,
    const float* __restrict__ A,
    const float* __restrict__ Whh_f, const float* __restrict__ Whh_b,
    const float* __restrict__ gWhh,
    const float* __restrict__ Wih_f, const float* __restrict__ Wih_b,
    const float* __restrict__ gWih, const float* __restrict__ genW,
    const float* __restrict__ bih_f, const float* __restrict__ bih_b,
    int* __restrict__ offs, int* __restrict__ rowmap, int* __restrict__ flags,
    float* __restrict__ biascat, float* __restrict__ asum,
    ushort* __restrict__ WgL, ushort* __restrict__ Wg16,
    ushort* __restrict__ Wcat, ushort* __restrict__ gWih_bf,
    ushort* __restrict__ genW_bf) {
  const int bid = blockIdx.x;
  const int tid = threadIdx.x;
  if (bid < 1) {                       // offsets
    if (tid == 0) {
      int o = 0;
      for (int b = 0; b < NB; ++b) { offs[b] = o; o += tlen[b]; }
    }
  } else if (bid < 4) {                // zero flags
    int i = (bid - 1) * 256 + tid;
    if (i < 768) flags[i] = 0;
  } else if (bid < 12) {               // biascat
    int i = (bid - 4) * 256 + tid;
    if (i < G4) biascat[i] = bih_f[i];
    else if (i < 2 * G4) biascat[i] = bih_b[i - G4];
  } else if (bid < 140) {              // rowmap (self prefix)
    int b = bid - 12;
    __shared__ int soff;
    if (tid == 0) {
      int o = 0;
      for (int k = 0; k < b; ++k) o += tlen[k];
      soff = o;
    }
    __syncthreads();
    int len = tlen[b], off0 = soff;
    for (int t = tid; t < len; t += 256) rowmap[off0 + t] = t * NB + b;
  } else if (bid < 1420) {             // asum: 4 rows/block, wave reduce
    int row = (bid - 140) * 4 + (tid >> 6);   // b*NT + t
    int lane = tid & 63;
    const float* p = A + (size_t)row * HW;
    float s = 0.f;
#pragma unroll
    for (int i = 0; i < 8; ++i) s += p[lane + i * 64];
#pragma unroll
    for (int off = 32; off > 0; off >>= 1) s += __shfl_down(s, off);
    if (lane == 0) asum[row] = 1.0f / s;
  } else if (bid < 1676) {
    seg_cvtf16(Whh_f, WgL, 4 * HL * HL / 4, bid - 1420);
  } else if (bid < 1932) {
    seg_cvtf16(Whh_b, WgL + 4 * HL * HL, 4 * HL * HL / 4, bid - 1676);
  } else if (bid < 2700) {
    seg_cvtf16(gWhh, Wg16, G3 * NC / 4, bid - 1932);
  } else if (bid < 3212) {
    seg_cvtbf(Wih_f, Wcat, G4 * NC / 4, bid - 2700);
  } else if (bid < 3724) {
    seg_cvtbf(Wih_b, Wcat + (size_t)G4 * NC, G4 * NC / 4, bid - 3212);
  } else if (bid < 5260) {
    seg_cvtbf(gWih, gWih_bf, G3 * XDIM / 4, bid - 3724);
  } else if (bid < 7760) {
    seg_cvtbf(genW, genW_bf, NG * NC / 4, bid - 5260);
  }
}

// teacher-forcing embedding into x16[:,:,512:1024] (bf16)
__global__ __launch_bounds__(128) void emb_kernel(const float* __restrict__ ce,
                                                  const int* __restrict__ text,
                                                  const int* __restrict__ tl,
                                                  const int* __restrict__ offs,
                                                  ushort* __restrict__ x16) {
  int bid = blockIdx.x;  // t*NB + b
  int t = bid >> 7, b = bid & 127;
  int tok = 0;
  if (t >= 2) {
    int p = t - 2;
    if (p < tl[b]) tok = text[offs[b] + p] + 1;
  }
  float4 v = *(const float4*)(ce + (size_t)tok * NC + threadIdx.x * 4);
  ushort4 u;
  u.x = (ushort)f2bf(v.x); u.y = (ushort)f2bf(v.y);
  u.z = (ushort)f2bf(v.z); u.w = (ushort)f2bf(v.w);
  *(ushort4*)(x16 + (size_t)bid * XDIM + NC + threadIdx.x * 4) = u;
}

// ---------------------------------------------------------------------------
// attention-pool MFMA kernel (R17-proven): per-b GEMM, fused f32->bf16
// staging, asum folded into B. Writes Cbf[(t*NB+b)*NC + c] bf16.
// ---------------------------------------------------------------------------
__global__ __launch_bounds__(256) void pool_mfma_kernel(
    const float* __restrict__ feat,   // [NB][NC][HW]
    const float* __restrict__ A,      // [NB][NT][HW]
    const float* __restrict__ asum,   // [NB*NT] = 1/sum
    ushort* __restrict__ Cbf) {       // [NT*NB][NC]
  __shared__ __align__(16) ushort Al[128 * 40];
  __shared__ __align__(16) ushort Bl[128 * 40];
  const int b = blockIdx.z;
  const int m0 = blockIdx.y * 128;
  const int tid = threadIdx.x;
  const int lane = tid & 63, wid = tid >> 6;
  const int wm = (wid >> 1) * 64, wn = (wid & 1) * 64;
  const int lr = lane & 15, lk = lane >> 4;

  f32x4_ acc[4][4];
#pragma unroll
  for (int i = 0; i < 4; ++i)
#pragma unroll
    for (int j = 0; j < 4; ++j) {
      acc[i][j][0] = 0.f; acc[i][j][1] = 0.f;
      acc[i][j][2] = 0.f; acc[i][j][3] = 0.f;
    }

  for (int k0 = 0; k0 < HW; k0 += 32) {
    __syncthreads();
#pragma unroll
    for (int it = 0; it < 2; ++it) {
      int ch = tid + it * 256;          // 0..511
      int rr = ch >> 2, kq = (ch & 3) * 8;
      const float* fa = feat + ((size_t)b * NC + (m0 + rr)) * HW + k0 + kq;
      float4 a0 = *(const float4*)fa;
      float4 a1 = *(const float4*)(fa + 4);
      ushort av[8] = {(ushort)f2bf(a0.x), (ushort)f2bf(a0.y), (ushort)f2bf(a0.z),
                      (ushort)f2bf(a0.w), (ushort)f2bf(a1.x), (ushort)f2bf(a1.y),
                      (ushort)f2bf(a1.z), (ushort)f2bf(a1.w)};
      *(uint4*)&Al[rr * 40 + kq] = *(const uint4*)av;
      int t = rr < NT ? rr : NT - 1;
      float s = asum[b * NT + t];
      const float* fb = A + ((size_t)b * NT + t) * HW + k0 + kq;
      float4 b0 = *(const float4*)fb;
      float4 b1 = *(const float4*)(fb + 4);
      ushort bv[8] = {(ushort)f2bf(b0.x * s), (ushort)f2bf(b0.y * s),
                      (ushort)f2bf(b0.z * s), (ushort)f2bf(b0.w * s),
                      (ushort)f2bf(b1.x * s), (ushort)f2bf(b1.y * s),
                      (ushort)f2bf(b1.z * s), (ushort)f2bf(b1.w * s)};
      *(uint4*)&Bl[rr * 40 + kq] = *(const uint4*)bv;
    }
    __syncthreads();
    s16x8 af[4], bf[4];
#pragma unroll
    for (int i = 0; i < 4; ++i)
      af[i] = *(const s16x8*)&Al[(wm + i * 16 + lr) * 40 + lk * 8];
#pragma unroll
    for (int i = 0; i < 4; ++i)
      bf[i] = *(const s16x8*)&Bl[(wn + i * 16 + lr) * 40 + lk * 8];
#pragma unroll
    for (int i = 0; i < 4; ++i)
#pragma unroll
      for (int j = 0; j < 4; ++j)
        acc[i][j] = __builtin_amdgcn_mfma_f32_16x16x32_bf16(af[i], bf[j], acc[i][j], 0, 0, 0);
  }

#pragma unroll
  for (int i = 0; i < 4; ++i) {
#pragma unroll
    for (int j = 0; j < 4; ++j) {
      int t = wn + j * 16 + lr;
      if (t >= NT) continue;
#pragma unroll
      for (int r = 0; r < 4; ++r) {
        int c = m0 + wm + i * 16 + lk * 4 + r;
        Cbf[((size_t)t * NB + b) * NC + c] = (ushort)f2bf(acc[i][j][r]);
      }
    }
  }
}

// ---------------------------------------------------------------------------
// bf16 MFMA GEMM (R14-proven): 128x128 tile, 4 waves 2x2, 16x16x32 mfma.
// global_load_lds staging with XOR-swizzled layout.
// ---------------------------------------------------------------------------
#if __has_builtin(__builtin_amdgcn_global_load_lds)
#define MG_ASYNC 1
#endif

#ifdef MG_ASYNC
#define MG_LDT 32
#else
#define MG_LDT 40
#endif

__global__ __launch_bounds__(256) void mgemm_kernel(
    int M, int N, int K,
    const ushort* __restrict__ A, const int* __restrict__ rowmap,
    const ushort* __restrict__ B, const float* __restrict__ bias,
    void* __restrict__ outp, long ldo, int outBf) {
  __shared__ __align__(16) ushort Al[128 * MG_LDT];
  __shared__ __align__(16) ushort Bl[128 * MG_LDT];
  const int m0 = blockIdx.y * 128, n0 = blockIdx.x * 128;
  const int tid = threadIdx.x;
  const int lane = tid & 63, wid = tid >> 6;
  const int wm = (wid >> 1) * 64, wn = (wid & 1) * 64;
  const int lr = lane & 15, lk = lane >> 4;

  f32x4_ acc[4][4];
#pragma unroll
  for (int i = 0; i < 4; ++i)
#pragma unroll
    for (int j = 0; j < 4; ++j) {
      acc[i][j][0] = 0.f; acc[i][j][1] = 0.f;
      acc[i][j][2] = 0.f; acc[i][j][3] = 0.f;
    }

#ifdef MG_ASYNC
  const int swsrc = (((lane & 3) ^ ((lane >> 2) & 3) ^ ((lane >> 4) & 3))) * 8;
  const int sA = (lr & 3) ^ ((lr >> 2) & 3);      // s(R) for read rows
  const int kofs = (lk ^ sA) * 8;                 // swizzled ushort col offset
#endif

  for (int k0 = 0; k0 < K; k0 += 32) {
    __syncthreads();
#ifdef MG_ASYNC
#pragma unroll
    for (int it = 0; it < 2; ++it) {
      const int qq = wid * 2 + it;                 // 16-row chunk, wave-uniform
      const int row = qq * 16 + (lane >> 2);       // local tile row
      int gm = m0 + row; if (gm >= M) gm = M - 1;
      long ar = rowmap ? (long)rowmap[gm] : (long)gm;
      const ushort* ga = A + ar * (long)K + k0 + swsrc;
      __builtin_amdgcn_global_load_lds(
          (const __attribute__((address_space(1))) void*)ga,
          (__attribute__((address_space(3))) void*)&Al[qq * 512], 16, 0, 0);
      int gn = n0 + row; if (gn >= N) gn = N - 1;
      const ushort* gb = B + (long)gn * K + k0 + swsrc;
      __builtin_amdgcn_global_load_lds(
          (const __attribute__((address_space(1))) void*)gb,
          (__attribute__((address_space(3))) void*)&Bl[qq * 512], 16, 0, 0);
    }
#else
#pragma unroll
    for (int it = 0; it < 2; ++it) {
      int ch = tid + it * 256;          // 0..511
      int rr = ch >> 2, kq = (ch & 3) * 8;
      int gm = m0 + rr; if (gm >= M) gm = M - 1;
      long ar = rowmap ? (long)rowmap[gm] : (long)gm;
      uint4 av = *(const uint4*)(A + ar * (long)K + k0 + kq);
      int gn = n0 + rr; if (gn >= N) gn = N - 1;
      uint4 bv = *(const uint4*)(B + (long)gn * K + k0 + kq);
      *(uint4*)&Al[rr * MG_LDT + kq] = av;
      *(uint4*)&Bl[rr * MG_LDT + kq] = bv;
    }
#endif
    __syncthreads();
    s16x8 af[4], bf[4];
#ifdef MG_ASYNC
#pragma unroll
    for (int i = 0; i < 4; ++i)
      af[i] = *(const s16x8*)&Al[(wm + i * 16 + lr) * 32 + kofs];
#pragma unroll
    for (int i = 0; i < 4; ++i)
      bf[i] = *(const s16x8*)&Bl[(wn + i * 16 + lr) * 32 + kofs];
#else
#pragma unroll
    for (int i = 0; i < 4; ++i)
      af[i] = *(const s16x8*)&Al[(wm + i * 16 + lr) * MG_LDT + lk * 8];
#pragma unroll
    for (int i = 0; i < 4; ++i)
      bf[i] = *(const s16x8*)&Bl[(wn + i * 16 + lr) * MG_LDT + lk * 8];
#endif
#pragma unroll
    for (int i = 0; i < 4; ++i)
#pragma unroll
      for (int j = 0; j < 4; ++j)
        acc[i][j] = __builtin_amdgcn_mfma_f32_16x16x32_bf16(af[i], bf[j], acc[i][j], 0, 0, 0);
  }

#pragma unroll
  for (int i = 0; i < 4; ++i) {
#pragma unroll
    for (int j = 0; j < 4; ++j) {
      int n = n0 + wn + j * 16 + lr;
      if (n >= N) continue;
      float bv = bias ? bias[n] : 0.f;
#pragma unroll
      for (int r = 0; r < 4; ++r) {
        int m = m0 + wm + i * 16 + lk * 4 + r;
        if (m >= M) continue;
        float v = acc[i][j][r] + bv;
        if (outBf) ((ushort*)outp)[(long)m * ldo + n] = (ushort)f2bf(v);
        else       ((float*)outp)[(long)m * ldo + n] = v;
      }
    }
  }
}

// ---------------------------------------------------------------------------
// LSTM sync recurrence (R17-proven; xg combined bf16 stride-2048):
// 64 blocks = 2 dirs x 4 batch-groups(32) x 8 j-chunks(32), 256 thr.
// ---------------------------------------------------------------------------
__global__ __launch_bounds__(256) void lstm_sync_kernel(
    const ushort* __restrict__ xgc,   // bf16 [NT*NB][2*G4]: cols dir*1024+g*256+j
    const ushort* __restrict__ W16,   // f16 [2][4*HL][HL]
    const float* __restrict__ bhh_f, const float* __restrict__ bhh_b,
    ushort* __restrict__ hbufL,       // f16 [2][2][8][NB][32]
    ushort* __restrict__ x16,         // bf16 [NT*NB][XDIM]
    int* __restrict__ flags) {
  const int dir = blockIdx.x >> 5;
  const int bg = (blockIdx.x >> 3) & 3;
  const int jc = blockIdx.x & 7;
  const float* bhh = dir ? bhh_b : bhh_f;
  const ushort* W = W16 + (size_t)dir * 4 * HL * HL;
  const int tid = threadIdx.x;
  const int lane = tid & 63, wid = tid >> 6;
  const int mt = wid >> 1, jsub = wid & 1;
  const int lr = lane & 15, lk = lane >> 4;

  __shared__ __align__(16) ushort Wl[8 * 128 * 40];  // [ktile][g*32+jj][40]

  // stage W chunk into LDS (one-time): 4096 uint4
  for (int i = tid; i < 4096; i += 256) {
    int kt = i >> 9, rem = i & 511;
    int row = rem >> 2, kq = rem & 3;
    int g = row >> 5, jj = row & 31;
    const ushort* src = W + ((size_t)(g * HL + jc * 32 + jj)) * HL + kt * 32 + kq * 8;
    *(uint4*)&Wl[(kt * 128 + row) * 40 + kq * 8] = *(const uint4*)src;
  }
  // zero own h slice (ping 0) with sc1 stores
  for (int i = tid; i < 1024; i += 256) {
    int bb = i >> 5, jl2 = i & 31;
    __hip_atomic_store(
        &hbufL[(((size_t)dir) * 8 + jc) * NB * 32 + (size_t)(bg * 32 + bb) * 32 + jl2],
        (ushort)0, __ATOMIC_RELAXED, __HIP_MEMORY_SCOPE_AGENT);
  }

  int* gfl = flags + (dir * 4 + bg) * 64;
  const int jl = jsub * 16 + lr;
  const int jg = jc * 32 + jl;
  const int bbase = bg * 32 + mt * 16;
  const int xcol = dir * G4 + jg;     // base col in combined xg
  const float bbi = bhh[jg], bbf = bhh[HL + jg];
  const float bbg = bhh[2 * HL + jg], bbo = bhh[3 * HL + jg];
  float creg[4] = {0.f, 0.f, 0.f, 0.f};
  float pxi[4], pxf[4], pxg[4], pxo[4];

  auto pref = [&](int s) {
    int tt = dir ? (NT - 1 - s) : s;
#pragma unroll
    for (int r = 0; r < 4; ++r) {
      int b = bbase + lk * 4 + r;
      const ushort* p = xgc + ((long)tt * NB + b) * (2 * G4) + xcol;
      pxi[r] = bf2f(p[0]);
      pxf[r] = bf2f(p[HL]);
      pxg[r] = bf2f(p[2 * HL]);
      pxo[r] = bf2f(p[3 * HL]);
    }
  };

  auto bar = [&](int step, int prefs) {
    __syncthreads();
    if (tid == 0)
      __hip_atomic_store(&gfl[jc], step, __ATOMIC_RELAXED, __HIP_MEMORY_SCOPE_AGENT);
    if (prefs >= 0) pref(prefs);
    if (tid < 8) {
      while (__hip_atomic_load(&gfl[tid], __ATOMIC_RELAXED, __HIP_MEMORY_SCOPE_AGENT) < step)
        __builtin_amdgcn_s_sleep(1);
    }
    __syncthreads();
  };

  bar(1, 0);   // publish W-stage-done + h zeros; prefetch xg(0)

  for (int s = 0; s < NT; ++s) {
    const int p = s & 1;
    const int tt = dir ? (NT - 1 - s) : s;
    f16x8 ha[8];
#pragma unroll
    for (int kt = 0; kt < 8; ++kt)
      ha[kt] = coh_load16(hbufL + (((size_t)p * 2 + dir) * 8 + kt) * NB * 32 +
                          (size_t)(bbase + lr) * 32 + lk * 8);
    f32x4_ ai = {0.f, 0.f, 0.f, 0.f};
    f32x4_ af = {0.f, 0.f, 0.f, 0.f};
    f32x4_ ag = {0.f, 0.f, 0.f, 0.f};
    f32x4_ ao = {0.f, 0.f, 0.f, 0.f};
#pragma unroll
    for (int kt = 0; kt < 8; ++kt) {
      f16x8 bi = *(const f16x8*)&Wl[(kt * 128 + 0  + jl) * 40 + lk * 8];
      f16x8 bf = *(const f16x8*)&Wl[(kt * 128 + 32 + jl) * 40 + lk * 8];
      f16x8 bg_ = *(const f16x8*)&Wl[(kt * 128 + 64 + jl) * 40 + lk * 8];
      f16x8 bo = *(const f16x8*)&Wl[(kt * 128 + 96 + jl) * 40 + lk * 8];
      ai = __builtin_amdgcn_mfma_f32_16x16x32_f16(ha[kt], bi, ai, 0, 0, 0);
      af = __builtin_amdgcn_mfma_f32_16x16x32_f16(ha[kt], bf, af, 0, 0, 0);
      ag = __builtin_amdgcn_mfma_f32_16x16x32_f16(ha[kt], bg_, ag, 0, 0, 0);
      ao = __builtin_amdgcn_mfma_f32_16x16x32_f16(ha[kt], bo, ao, 0, 0, 0);
    }
    ushort* hwc = hbufL + (((size_t)(p ^ 1) * 2 + dir) * 8 + jc) * NB * 32;
#pragma unroll
    for (int r = 0; r < 4; ++r) {
      int b = bbase + lk * 4 + r;
      long row = (long)tt * NB + b;
      float gi = pxi[r] + ai[r] + bbi;
      float gf = pxf[r] + af[r] + bbf;
      float gg = pxg[r] + ag[r] + bbg;
      float go = pxo[r] + ao[r] + bbo;
      creg[r] = sigm(gf) * creg[r] + sigm(gi) * tanhf(gg);
      float hn = sigm(go) * tanhf(creg[r]);
      __hip_atomic_store(&hwc[(size_t)b * 32 + jl], f2hs(hn),
                         __ATOMIC_RELAXED, __HIP_MEMORY_SCOPE_AGENT);
      x16[row * XDIM + dir * HL + jg] = (ushort)f2bf(hn);
    }
    if (s + 1 < NT) bar(s + 2, s + 1);
  }
}

// ---------------------------------------------------------------------------
// GRU sync recurrence (R15-proven): 64 blocks = 4 batch-groups x 16 j-chunks.
// ---------------------------------------------------------------------------
__global__ __launch_bounds__(256) void gru_sync_kernel(
    const ushort* __restrict__ xg,    // bf16 [NT*NB][G3]
    const ushort* __restrict__ Wf,    // f16 [G3][NC]
    const float* __restrict__ bhh,
    ushort* __restrict__ hbuf,        // f16 chunked [2][16][NB][32]
    ushort* __restrict__ gout,        // bf16 flat [NT*NB][NC]
    int* __restrict__ flags) {
  const int bg = blockIdx.x >> 4, jc = blockIdx.x & 15;
  const int tid = threadIdx.x;
  const int lane = tid & 63, wid = tid >> 6;
  const int mt = wid >> 1, jsub = wid & 1;
  const int lr = lane & 15, lk = lane >> 4;

  __shared__ __align__(16) ushort Wl[16 * 96 * 40];  // [ktile][g*32+jj][40]

  for (int i = tid; i < 6144; i += 256) {
    int kt = i / 384, rem = i - kt * 384;
    int row = rem >> 2, kq = rem & 3;
    int g = row >> 5, jj = row & 31;
    const ushort* src = Wf + ((size_t)(g * NC + jc * 32 + jj)) * NC + kt * 32 + kq * 8;
    *(uint4*)&Wl[(kt * 96 + row) * 40 + kq * 8] = *(const uint4*)src;
  }
  for (int i = tid; i < 1024; i += 256) {
    int bb = i >> 5, jl2 = i & 31;
    __hip_atomic_store(&hbuf[((size_t)jc * NB + (bg * 32 + bb)) * 32 + jl2],
                       (ushort)0, __ATOMIC_RELAXED, __HIP_MEMORY_SCOPE_AGENT);
  }

  int* gfl = flags + bg * 64;                // 256B per group
  const int jl = jsub * 16 + lr;             // local j within chunk
  const int jg = jc * 32 + jl;               // global j
  const int bbase = bg * 32 + mt * 16;       // A/C m-tile batch base
  const float bb0 = bhh[jg], bb1 = bhh[NC + jg], bb2 = bhh[2 * NC + jg];
  float hreg[4] = {0.f, 0.f, 0.f, 0.f};
  float pxr[4], pxz[4], pxn[4];

  auto pref = [&](int t) {
#pragma unroll
    for (int r = 0; r < 4; ++r) {
      int b = bbase + lk * 4 + r;
      long row = (long)t * NB + b;
      pxr[r] = bf2f(xg[row * G3 + jg]);
      pxz[r] = bf2f(xg[row * G3 + NC + jg]);
      pxn[r] = bf2f(xg[row * G3 + 2 * NC + jg]);
    }
  };

  auto bar = [&](int step, int preft) {
    __syncthreads();
    if (tid == 0)
      __hip_atomic_store(&gfl[jc], step, __ATOMIC_RELAXED, __HIP_MEMORY_SCOPE_AGENT);
    if (preft >= 0) pref(preft);
    if (tid < 16) {
      while (__hip_atomic_load(&gfl[tid], __ATOMIC_RELAXED, __HIP_MEMORY_SCOPE_AGENT) < step)
        __builtin_amdgcn_s_sleep(1);
    }
    __syncthreads();
  };

  bar(1, 0);   // publish W-stage-done + h zeros; prefetch xg(0)

  for (int t = 0; t < NT; ++t) {
    const int p = t & 1;
    f16x8 ha[16];
#pragma unroll
    for (int kt = 0; kt < 16; ++kt)
      ha[kt] = coh_load16(hbuf + ((size_t)(p * 16 + kt) * NB + (bbase + lr)) * 32 + lk * 8);
    f32x4_ ar = {0.f, 0.f, 0.f, 0.f};
    f32x4_ az = {0.f, 0.f, 0.f, 0.f};
    f32x4_ an = {0.f, 0.f, 0.f, 0.f};
#pragma unroll
    for (int kt = 0; kt < 16; ++kt) {
      f16x8 br = *(const f16x8*)&Wl[(kt * 96 + 0  + jl) * 40 + lk * 8];
      f16x8 bz = *(const f16x8*)&Wl[(kt * 96 + 32 + jl) * 40 + lk * 8];
      f16x8 bn = *(const f16x8*)&Wl[(kt * 96 + 64 + jl) * 40 + lk * 8];
      ar = __builtin_amdgcn_mfma_f32_16x16x32_f16(ha[kt], br, ar, 0, 0, 0);
      az = __builtin_amdgcn_mfma_f32_16x16x32_f16(ha[kt], bz, az, 0, 0, 0);
      an = __builtin_amdgcn_mfma_f32_16x16x32_f16(ha[kt], bn, an, 0, 0, 0);
    }
    ushort* hwc = hbuf + ((size_t)((p ^ 1) * 16 + jc)) * NB * 32;
#pragma unroll
    for (int r = 0; r < 4; ++r) {
      int b = bbase + lk * 4 + r;
      long row = (long)t * NB + b;
      float rr = sigm(pxr[r] + ar[r] + bb0);
      float zz = sigm(pxz[r] + az[r] + bb1);
      float nn = tanhf(pxn[r] + rr * (an[r] + bb2));
      float h = (1.f - zz) * nn + zz * hreg[r];
      hreg[r] = h;
      __hip_atomic_store(&hwc[(size_t)b * 32 + jl], f2hs(h),
                         __ATOMIC_RELAXED, __HIP_MEMORY_SCOPE_AGENT);
      gout[row * NC + jg] = (ushort)f2bf(h);
    }
    if (t + 1 < NT) bar(t + 2, t + 1);
  }
}

// ---------------------------------------------------------------------------
extern "C" void kernel_launch(void* const* d_in, const int* in_sizes, int n_in,
                              void* d_out, int out_size, void* d_ws, size_t ws_size,
                              hipStream_t stream) {
  const float* feature = (const float*)d_in[0];
  const float* A       = (const float*)d_in[1];
  const int*   text    = (const int*)d_in[2];
  const int*   tlen    = (const int*)d_in[3];
  const float* Wih_f   = (const float*)d_in[4];
  const float* Whh_f   = (const float*)d_in[5];
  const float* bih_f   = (const float*)d_in[6];
  const float* bhh_f   = (const float*)d_in[7];
  const float* Wih_b   = (const float*)d_in[8];
  const float* Whh_b   = (const float*)d_in[9];
  const float* bih_b   = (const float*)d_in[10];
  const float* bhh_b   = (const float*)d_in[11];
  const float* gWih    = (const float*)d_in[12];
  const float* gWhh    = (const float*)d_in[13];
  const float* gbih    = (const float*)d_in[14];
  const float* gbhh    = (const float*)d_in[15];
  const float* genW    = (const float*)d_in[16];
  const float* genb    = (const float*)d_in[17];
  const float* cemb    = (const float*)d_in[18];
  float* out = (float*)d_out;
  const int total = in_sizes[2];

  char* ws = (char*)d_ws;
  size_t off = 0;
  auto alloc = [&](size_t bytes) -> void* {
    void* p = ws + off;
    off += (bytes + 255) & ~(size_t)255;
    return p;
  };
  float*    asum   = (float*)alloc((size_t)NB * NT * 4);
  int*      offs   = (int*)alloc(NB * 4);
  int*      rowmap = (int*)alloc((size_t)NB * NT * 4);
  int*      flags  = (int*)alloc(12 * 64 * 4);                  // GRU 4 + LSTM 8 groups
  float*    biascat= (float*)alloc(2 * G4 * 4);
  ushort*   xgcat  = (ushort*)alloc((size_t)NT * NB * 2 * G4 * 2); // 21MB bf16; later gxg
  ushort*   xbuf_bf= (ushort*)alloc((size_t)NT * NB * XDIM * 2);// 10.5MB: x bf16
  ushort*   WgL    = (ushort*)alloc((size_t)2 * 4 * HL * HL * 2);  // LSTM Whh f16, 1 MB
  ushort*   Wg16   = (ushort*)alloc((size_t)G3 * NC * 2);       // GRU Whh f16, 1.5 MB
  ushort*   Wcat   = (ushort*)alloc((size_t)2 * G4 * NC * 2);   // LSTM Wih concat bf16, 2 MB
  ushort*   gWih_bf= (ushort*)alloc((size_t)G3 * XDIM * 2);     // 3 MB
  ushort*   genW_bf= (ushort*)alloc((size_t)NG * NC * 2);       // 5.12 MB
  ushort*   hbuf   = (ushort*)alloc((size_t)2 * 16 * NB * 32 * 2);    // GRU h, 256KB
  ushort*   hbufL  = (ushort*)alloc((size_t)2 * 2 * 8 * NB * 32 * 2); // LSTM h, 256KB
  ushort*   Cbf    = (ushort*)alloc((size_t)NT * NB * NC * 2);  // 5.25MB: C bf16 / gout bf16
  ushort*   gxg    = xgcat;                                     // bf16 [5120][1536] (after lstm)
  ushort*   gout_bf = Cbf;

  // --- ALL setup work in ONE fused launch ---
  prep_kernel<<<7760, 256, 0, stream>>>(
      tlen, A, Whh_f, Whh_b, gWhh, Wih_f, Wih_b, gWih, genW, bih_f, bih_b,
      offs, rowmap, flags, biascat, asum,
      WgL, Wg16, Wcat, gWih_bf, genW_bf);

  // --- attention pooling: fused f32->bf16 MFMA, writes Cbf directly ---
  pool_mfma_kernel<<<dim3(1, 4, NB), 256, 0, stream>>>(feature, A, asum, Cbf);

  // --- LSTM input projections: ONE fused mgemm (N=2048) -> xgcat bf16 ---
  mgemm_kernel<<<dim3(2 * G4 / 128, NT * NB / 128), 256, 0, stream>>>(
      NT * NB, 2 * G4, NC, Cbf, nullptr, Wcat, biascat, xgcat, (long)(2 * G4), 1);

  // --- LSTM recurrence: sync groups, LDS-resident W, writes bf16 x ---
  lstm_sync_kernel<<<64, 256, 0, stream>>>(
      xgcat, WgL, bhh_f, bhh_b, hbufL, xbuf_bf, flags + 256);

  // --- embedding into x[:,:,512:1024] (bf16) ---
  emb_kernel<<<NT * NB, 128, 0, stream>>>(cemb, text, tlen, offs, xbuf_bf);

  // --- GRU input projection (xgcat consumed -> gxg reuses its region) ---
  mgemm_kernel<<<dim3(G3 / 128, NT * NB / 128), 256, 0, stream>>>(
      NT * NB, G3, XDIM, xbuf_bf, nullptr, gWih_bf, gbih, gxg, (long)G3, 1);

  // --- GRU recurrence: sync groups, sc1 h exchange, flat gout ---
  gru_sync_kernel<<<64, 256, 0, stream>>>(gxg, Wg16, gbhh, hbuf, gout_bf, flags);

  // --- vocab projection, ragged rows straight into d_out ---
  mgemm_kernel<<<dim3((NG + 127) / 128, (total + 127) / 128), 256, 0, stream>>>(
      total, NG, NC, gout_bf, rowmap, genW_bf, genb, out, (long)NG, 0);
}